// Round 1
// 499.033 us; speedup vs baseline: 1.0489x; 1.0489x over previous
//
#include <hip/hip_runtime.h>
#include <cstdint>

// Problem constants
#define Bc 32
#define Lc 2048
#define Hc 512
#define Cc 50
#define PCc 52        // P3 row stride (52 floats = 208 B, 16B-aligned)
#define Mc (Bc*Lc)    // 65536 rows

typedef short s8v   __attribute__((ext_vector_type(8)));   // 8 bf16 (4 VGPRs)
typedef float f4v   __attribute__((ext_vector_type(4)));   // MFMA C/D

__device__ inline unsigned short f2bf(float f) {            // RNE fp32->bf16
    unsigned int u = __float_as_uint(f);
    u += 0x7fffu + ((u >> 16) & 1u);
    return (unsigned short)(u >> 16);
}
__device__ inline float bf2f(unsigned short h) {
    return __uint_as_float(((unsigned int)h) << 16);
}
// tanh(x) = 1 - 2/(e^{2x}+1): ~5 VALU ops (mul, v_exp, add, rcp, fma).
// Saturates exactly (+inf -> 1, 0 -> -1); abs err ~1e-5 << bf16 rounding.
__device__ inline float fast_tanh(float x) {
    float e = __expf(2.0f * x);
    return 1.0f - 2.0f / (e + 1.0f);
}
__device__ inline void gl_lds16(const unsigned short* g, unsigned short* l) {
    __builtin_amdgcn_global_load_lds(
        (const __attribute__((address_space(1))) unsigned int*)g,
        (__attribute__((address_space(3))) unsigned int*)l, 16, 0, 0);
}

// ---------------------------------------------------------------------------
// fp32 -> bf16 bulk convert (keys). 8 elements/thread.
// ---------------------------------------------------------------------------
__global__ __launch_bounds__(256)
void f32_to_bf16_kernel(const float* __restrict__ in, unsigned short* __restrict__ out)
{
    size_t i = ((size_t)blockIdx.x * 256 + threadIdx.x) * 8;
    float4 a = *(const float4*)(in + i);
    float4 b = *(const float4*)(in + i + 4);
    s8v o;
    o[0]=f2bf(a.x); o[1]=f2bf(a.y); o[2]=f2bf(a.z); o[3]=f2bf(a.w);
    o[4]=f2bf(b.x); o[5]=f2bf(b.y); o[6]=f2bf(b.z); o[7]=f2bf(b.w);
    *(s8v*)(out + i) = o;
}

// ---------------------------------------------------------------------------
// Convert W1, W2 -> bf16; W3 (50x512) -> bf16 padded to 64x512 (zero rows).
// ---------------------------------------------------------------------------
__global__ __launch_bounds__(256)
void convert_weights_kernel(const float* __restrict__ W1, const float* __restrict__ W2,
                            const float* __restrict__ W3,
                            unsigned short* __restrict__ W1b,
                            unsigned short* __restrict__ W2b,
                            unsigned short* __restrict__ W3b)
{
    int e = (blockIdx.x * 256 + threadIdx.x) * 8;
    if (e >= 524288) {                       // W3 padded region
        int off = e - 524288;
        int row = off >> 9;
        s8v o;
        #pragma unroll
        for (int j = 0; j < 8; ++j)
            o[j] = (row < Cc) ? (short)f2bf(W3[off + j]) : (short)0;
        *(s8v*)(W3b + off) = o;
        return;
    }
    const float* src = (e < 262144) ? W1 : W2;
    unsigned short* dst = (e < 262144) ? W1b : W2b;
    int off = (e < 262144) ? e : e - 262144;
    float4 a = *(const float4*)(src + off);
    float4 b = *(const float4*)(src + off + 4);
    s8v o;
    o[0]=f2bf(a.x); o[1]=f2bf(a.y); o[2]=f2bf(a.z); o[3]=f2bf(a.w);
    o[4]=f2bf(b.x); o[5]=f2bf(b.y); o[6]=f2bf(b.z); o[7]=f2bf(b.w);
    *(s8v*)(dst + off) = o;
}

// ---------------------------------------------------------------------------
// V (fp32, [b][l][h]) -> Vt (bf16, [b][h][l]).  64x64 LDS tile transpose.
// ---------------------------------------------------------------------------
__global__ __launch_bounds__(256)
void transpose_v_kernel(const float* __restrict__ V, unsigned short* __restrict__ Vt)
{
    __shared__ float tile[64 * 65];
    const int l0 = blockIdx.x * 64;
    const int h0 = blockIdx.y * 64;
    const int b  = blockIdx.z;
    const int tid = threadIdx.x;
    const int li = tid >> 2;          // 0..63
    const int hq = (tid & 3) * 4;     // 0,4,8,12

    const float* src = V + ((size_t)(b * Lc + l0 + li)) * Hc + h0 + hq;
    #pragma unroll
    for (int j = 0; j < 4; ++j) {
        float4 v = *(const float4*)(src + 16 * j);
        float* d = &tile[li * 65 + hq + 16 * j];
        d[0] = v.x; d[1] = v.y; d[2] = v.z; d[3] = v.w;
    }
    __syncthreads();

    const int lane = tid & 63;
    const int w    = tid >> 6;
    #pragma unroll
    for (int i = 0; i < 16; ++i) {
        int hr = i * 4 + w;           // h row within tile
        unsigned short* dst = Vt + ((size_t)(b * Hc + h0 + hr)) * Lc + l0 + lane;
        *dst = f2bf(tile[lane * 65 + hr]);
    }
}

// ---------------------------------------------------------------------------
// MFMA GEMM: Out = f(A @ W^T), 128x128 tile, BK=32, m97 structure.
// mode 0: Out = bf16(fast_tanh(acc)); mode 1: Out = bf16(A[m,j]+fast_tanh(acc))
//
// Round-1 changes:
//  * 1-D grid with XCD-grouped mapping: the 4 column-blocks that share the
//    same 128 A-rows are dispatched to the SAME XCD (bid&7), so A re-reads
//    hit the local 4 MiB L2 instead of re-fetching from HBM (FETCH ~2.4x ideal
//    before).
//  * Vectorized epilogue: acc -> fp32 LDS tile (32x133, pad breaks bank
//    aliasing) in 4 quarter-phases, then coalesced ushort4 stores (8 B/lane)
//    and vectorized ushort4 residual loads. Replaces 64 scalar 2-B stores +
//    64 scalar 2-B loads per thread. Numerics identical (tanh fp32, fp32 add,
//    single bf16 rounding).
// ---------------------------------------------------------------------------
__global__ __launch_bounds__(256)
void mfma_gemm512(const unsigned short* __restrict__ Ab,
                  const unsigned short* __restrict__ Wb,
                  unsigned short* __restrict__ Ob, int mode)
{
    __shared__ alignas(16) unsigned short As[128 * 32];
    __shared__ alignas(16) unsigned short Bs[128 * 32];
    __shared__ alignas(16) float Esf[32 * 133];      // epilogue quarter-tile
    const int tid = threadIdx.x;
    const int w = tid >> 6, l = tid & 63;

    // XCD-grouped block mapping: grid = 2048 linear blocks.
    // xcd = bid&7 (dispatch round-robin); each XCD owns 64 consecutive
    // row-blocks x 4 col-blocks, with the 4 col-blocks adjacent in time.
    const int bid = blockIdx.x;
    const int ixd = bid >> 3;                 // 0..255 within XCD
    const int y   = (bid & 7) * 64 + (ixd >> 2);
    const int x   = ixd & 3;
    const int j0 = x * 128;
    const int i0 = y * 128;

    const int sr  = w * 16 + (l >> 2);
    const int kg8 = (l & 3) * 8;
    const unsigned short* Ag0 = Ab + (size_t)(i0 + sr) * 512 + kg8;
    const unsigned short* Ag1 = Ag0 + (size_t)64 * 512;
    const unsigned short* Bg0 = Wb + (size_t)(j0 + sr) * 512 + kg8;
    const unsigned short* Bg1 = Bg0 + (size_t)64 * 512;
    unsigned short* Al0 = As + w * 512;
    unsigned short* Al1 = As + 2048 + w * 512;
    unsigned short* Bl0 = Bs + w * 512;
    unsigned short* Bl1 = Bs + 2048 + w * 512;

    const int wm = (w & 1) * 64, wn = (w >> 1) * 64;
    const int fr = l & 15;
    const int fq = (l >> 4) * 8;

    f4v acc[4][4];
    #pragma unroll
    for (int r = 0; r < 4; ++r)
        #pragma unroll
        for (int c = 0; c < 4; ++c) acc[r][c] = (f4v){0.f, 0.f, 0.f, 0.f};

    for (int k0 = 0; k0 < 512; k0 += 32) {
        gl_lds16(Ag0 + k0, Al0);
        gl_lds16(Ag1 + k0, Al1);
        gl_lds16(Bg0 + k0, Bl0);
        gl_lds16(Bg1 + k0, Bl1);
        __syncthreads();
        s8v af[4], bf[4];
        #pragma unroll
        for (int r = 0; r < 4; ++r)
            af[r] = *(const s8v*)&As[(wm + r * 16 + fr) * 32 + fq];
        #pragma unroll
        for (int c = 0; c < 4; ++c)
            bf[c] = *(const s8v*)&Bs[(wn + c * 16 + fr) * 32 + fq];
        #pragma unroll
        for (int r = 0; r < 4; ++r)
            #pragma unroll
            for (int c = 0; c < 4; ++c)
                acc[r][c] = __builtin_amdgcn_mfma_f32_16x16x32_bf16(
                    af[r], bf[c], acc[r][c], 0, 0, 0);
        __syncthreads();
    }

    // Epilogue: 4 quarter-phases (32 rows each). Owner waves (w&1)==(h>>1)
    // deposit fp32 tanh(acc) into Esf; then all 256 threads stream it out
    // coalesced: per round, f4v LDS read -> ushort4 global store (+ ushort4
    // residual load in mode 1).
    #pragma unroll
    for (int h = 0; h < 4; ++h) {
        if (h) __syncthreads();              // previous phase's readers done
        if ((w & 1) == (h >> 1)) {
            const int rr = (h & 1) * 2;
            #pragma unroll
            for (int r = 0; r < 2; ++r)
                #pragma unroll
                for (int c = 0; c < 4; ++c)
                    #pragma unroll
                    for (int v = 0; v < 4; ++v) {
                        int row = r * 16 + (l >> 4) * 4 + v;   // 0..31
                        int col = wn + c * 16 + fr;            // 0..127
                        Esf[row * 133 + col] = fast_tanh(acc[rr + r][c][v]);
                    }
        }
        __syncthreads();
        #pragma unroll
        for (int t = 0; t < 4; ++t) {
            int chunk = t * 256 + tid;       // 0..1023
            int row = chunk >> 5;            // 0..31
            int c4  = (chunk & 31) * 4;      // 0..124
            f4v val = *(const f4v*)&Esf[row * 133 + c4];
            size_t gr   = (size_t)(i0 + (h >> 1) * 64 + (h & 1) * 32 + row);
            size_t goff = gr * 512 + j0 + c4;
            ushort4 o;
            if (mode) {
                ushort4 a = *(const ushort4*)(Ab + goff);
                o.x = f2bf(val[0] + bf2f(a.x));
                o.y = f2bf(val[1] + bf2f(a.y));
                o.z = f2bf(val[2] + bf2f(a.z));
                o.w = f2bf(val[3] + bf2f(a.w));
            } else {
                o.x = f2bf(val[0]); o.y = f2bf(val[1]);
                o.z = f2bf(val[2]); o.w = f2bf(val[3]);
            }
            *(ushort4*)(Ob + goff) = o;
        }
    }
}

// ---------------------------------------------------------------------------
// MFMA GEMM3: P3 = S @ W3^T (N=50 padded 64), fp32 out, row stride PCc=52.
// ---------------------------------------------------------------------------
__global__ __launch_bounds__(256)
void mfma_gemm_p3(const unsigned short* __restrict__ Sb,
                  const unsigned short* __restrict__ W3b,
                  float* __restrict__ P3)
{
    __shared__ alignas(16) unsigned short As[128 * 32];
    __shared__ alignas(16) unsigned short Bs[64 * 32];
    const int tid = threadIdx.x;
    const int w = tid >> 6, l = tid & 63;
    const int i0 = blockIdx.x * 128;

    const int sr  = w * 16 + (l >> 2);
    const int kg8 = (l & 3) * 8;
    const unsigned short* Ag0 = Sb + (size_t)(i0 + sr) * 512 + kg8;
    const unsigned short* Ag1 = Ag0 + (size_t)64 * 512;
    const unsigned short* Bg  = W3b + (size_t)sr * 512 + kg8;
    unsigned short* Al0 = As + w * 512;
    unsigned short* Al1 = As + 2048 + w * 512;
    unsigned short* Bl  = Bs + w * 512;

    const int wm = w * 32;
    const int fr = l & 15;
    const int fq = (l >> 4) * 8;

    f4v acc[2][4];
    #pragma unroll
    for (int r = 0; r < 2; ++r)
        #pragma unroll
        for (int c = 0; c < 4; ++c) acc[r][c] = (f4v){0.f, 0.f, 0.f, 0.f};

    for (int k0 = 0; k0 < 512; k0 += 32) {
        gl_lds16(Ag0 + k0, Al0);
        gl_lds16(Ag1 + k0, Al1);
        gl_lds16(Bg + k0, Bl);
        __syncthreads();
        s8v af[2], bf[4];
        #pragma unroll
        for (int r = 0; r < 2; ++r)
            af[r] = *(const s8v*)&As[(wm + r * 16 + fr) * 32 + fq];
        #pragma unroll
        for (int c = 0; c < 4; ++c)
            bf[c] = *(const s8v*)&Bs[(c * 16 + fr) * 32 + fq];
        #pragma unroll
        for (int r = 0; r < 2; ++r)
            #pragma unroll
            for (int c = 0; c < 4; ++c)
                acc[r][c] = __builtin_amdgcn_mfma_f32_16x16x32_bf16(
                    af[r], bf[c], acc[r][c], 0, 0, 0);
        __syncthreads();
    }

    #pragma unroll
    for (int r = 0; r < 2; ++r)
        #pragma unroll
        for (int v = 0; v < 4; ++v) {
            const int row = i0 + wm + r * 16 + (l >> 4) * 4 + v;
            #pragma unroll
            for (int c = 0; c < 4; ++c) {
                const int col = c * 16 + fr;
                if (col < Cc) P3[(size_t)row * PCc + col] = acc[r][c][v];
            }
        }
}

// ---------------------------------------------------------------------------
// sent_lens dtype hedge (int64 vs int32 auto-detect).
// ---------------------------------------------------------------------------
__global__ __launch_bounds__(64)
void normalize_lens_kernel(const int* __restrict__ raw, int* __restrict__ lens)
{
    __shared__ int is64;
    if (threadIdx.x == 0) {
        int orv = 0;
        for (int i = 1; i < 32; i += 2) orv |= raw[i];
        is64 = (orv == 0) ? 1 : 0;
    }
    __syncthreads();
    int b = threadIdx.x;
    if (b < Bc) lens[b] = is64 ? raw[2*b] : raw[b];
}

// ---------------------------------------------------------------------------
// kq-fill + avgpool3(count_include_pad=False) + softmax + mask.
// P3 rows padded to 52 floats -> 13 dwordx4 loads per row (vs 50 scalar).
// attn/smooth rows stored as 25 float2 each. attnT stores stay scalar
// (coalesced across lanes: consecutive l -> 128 B per wave-instr).
// Pad cols 50/51 are garbage but never used in pool/softmax math.
// ---------------------------------------------------------------------------
__global__ __launch_bounds__(256)
void pool_softmax_kernel(const float* __restrict__ P3, const int* __restrict__ lens,
                         float* __restrict__ out_attn, float* __restrict__ out_smooth,
                         unsigned short* __restrict__ attnT)
{
    const int idx = blockIdx.x * 256 + threadIdx.x;   // b*L + l
    const int b = idx >> 11;
    const int l = idx & (Lc - 1);
    const int len = lens[b];
    const float* base = P3 + (size_t)b * Lc * PCc;

    const int  r0 = min(l, len - 1);
    const bool hm = (l > 0);
    const bool hp = (l < Lc - 1);
    const int  rm = hm ? min(l - 1, len - 1) : 0;
    const int  rp = hp ? min(l + 1, len - 1) : 0;
    const float rcnt = 1.f / (1.f + (hm ? 1.f : 0.f) + (hp ? 1.f : 0.f));

    float sm[PCc];
    const float* p0 = base + (size_t)r0 * PCc;
    #pragma unroll
    for (int q = 0; q < 13; ++q) {
        f4v v = *(const f4v*)(p0 + q * 4);
        sm[q*4+0] = v[0]; sm[q*4+1] = v[1]; sm[q*4+2] = v[2]; sm[q*4+3] = v[3];
    }
    if (hm) {
        const float* p = base + (size_t)rm * PCc;
        #pragma unroll
        for (int q = 0; q < 13; ++q) {
            f4v v = *(const f4v*)(p + q * 4);
            sm[q*4+0] += v[0]; sm[q*4+1] += v[1]; sm[q*4+2] += v[2]; sm[q*4+3] += v[3];
        }
    }
    if (hp) {
        const float* p = base + (size_t)rp * PCc;
        #pragma unroll
        for (int q = 0; q < 13; ++q) {
            f4v v = *(const f4v*)(p + q * 4);
            sm[q*4+0] += v[0]; sm[q*4+1] += v[1]; sm[q*4+2] += v[2]; sm[q*4+3] += v[3];
        }
    }

    float mx = -1e30f;
    #pragma unroll
    for (int c = 0; c < Cc; ++c) {
        sm[c] *= rcnt;
        mx = fmaxf(mx, sm[c]);
    }
    float* srow = out_smooth + (size_t)idx * Cc;
    #pragma unroll
    for (int q = 0; q < 25; ++q) {
        float2 v = make_float2(sm[q*2], sm[q*2+1]);
        *(float2*)(srow + q * 2) = v;
    }

    float sum = 0.f;
    #pragma unroll
    for (int c = 0; c < Cc; ++c) {
        float e = __expf(sm[c] - mx);
        sm[c] = e;
        sum += e;
    }
    const float inv = 1.f / sum;
    const bool valid = (l < len);
    const float scale = valid ? inv : 0.f;
    float* arow = out_attn + (size_t)idx * Cc;
    unsigned short* trow = attnT + (size_t)b * 64 * Lc + l;
    #pragma unroll
    for (int c = 0; c < Cc; ++c) sm[c] *= scale;
    #pragma unroll
    for (int q = 0; q < 25; ++q)
        *(float2*)(arow + q * 2) = make_float2(sm[q*2], sm[q*2+1]);
    #pragma unroll
    for (int c = 0; c < Cc; ++c)
        trow[(size_t)c * Lc] = f2bf(sm[c]);
}

// ---------------------------------------------------------------------------
// class_inputs[b,c,h] = sum_l attn[b,l,c] * V[b,l,h]  -- MFMA (unchanged).
// ---------------------------------------------------------------------------
__global__ __launch_bounds__(256)
void class_mfma_kernel(const unsigned short* __restrict__ attnT,
                       const unsigned short* __restrict__ Vt,
                       float* __restrict__ out_class)
{
    __shared__ alignas(16) unsigned short As[64 * 32];    // 4 KB
    __shared__ alignas(16) unsigned short Bs[128 * 32];   // 8 KB
    const int tid = threadIdx.x;
    const int w = tid >> 6, l = tid & 63;
    const int n0 = blockIdx.x * 128;
    const int b  = blockIdx.y;
    const int kb = blockIdx.z * 512;

    const int sr  = w * 16 + (l >> 2);   // 0..63
    const int kg8 = (l & 3) * 8;
    const unsigned short* Ag  = attnT + ((size_t)b * 64 + sr) * Lc + kg8;
    const unsigned short* Bg0 = Vt + ((size_t)(b * Hc + n0 + sr)) * Lc + kg8;
    const unsigned short* Bg1 = Bg0 + (size_t)64 * Lc;
    unsigned short* Al  = As + w * 512;
    unsigned short* Bl0 = Bs + w * 512;
    unsigned short* Bl1 = Bs + 2048 + w * 512;

    const int fr = l & 15;
    const int fq = (l >> 4) * 8;

    f4v acc[4][2];
    #pragma unroll
    for (int r = 0; r < 4; ++r)
        #pragma unroll
        for (int c = 0; c < 2; ++c) acc[r][c] = (f4v){0.f, 0.f, 0.f, 0.f};

    for (int k0 = kb; k0 < kb + 512; k0 += 32) {
        gl_lds16(Ag + k0, Al);
        gl_lds16(Bg0 + k0, Bl0);
        gl_lds16(Bg1 + k0, Bl1);
        __syncthreads();
        s8v af[4], bf[2];
        #pragma unroll
        for (int r = 0; r < 4; ++r)
            af[r] = *(const s8v*)&As[(r * 16 + fr) * 32 + fq];
        #pragma unroll
        for (int c = 0; c < 2; ++c)
            bf[c] = *(const s8v*)&Bs[(w * 32 + c * 16 + fr) * 32 + fq];
        #pragma unroll
        for (int r = 0; r < 4; ++r)
            #pragma unroll
            for (int c = 0; c < 2; ++c)
                acc[r][c] = __builtin_amdgcn_mfma_f32_16x16x32_bf16(
                    af[r], bf[c], acc[r][c], 0, 0, 0);
        __syncthreads();
    }

    #pragma unroll
    for (int r = 0; r < 4; ++r)
        #pragma unroll
        for (int v = 0; v < 4; ++v) {
            const int m = r * 16 + (l >> 4) * 4 + v;   // class index
            if (m < Cc) {
                #pragma unroll
                for (int c = 0; c < 2; ++c) {
                    const int h = n0 + w * 32 + c * 16 + fr;
                    atomicAdd(out_class + ((size_t)b * Cc + m) * Hc + h,
                              acc[r][c][v]);
                }
            }
        }
}

// ---------------------------------------------------------------------------
// Workspace layout (~202 MiB, overlays exploit stream ordering):
//   off 0      : Akv bf16 (64 MiB)      -> later P3 fp32 stride-52 (13.6 MiB)
//   off 64 MiB : P1b bf16 (64 MiB)      -> later Vt bf16 (64 MiB)
//   off 128 MiB: Sb  bf16 (64 MiB)
//   off 192 MiB: W1b, W2b (0.5 MiB each), W3b (64 KiB)
//   off 194 MiB: attnT bf16 32x64x2048 (8 MiB)
//   off 202 MiB: lens (128 B)
// ---------------------------------------------------------------------------
extern "C" void kernel_launch(void* const* d_in, const int* in_sizes, int n_in,
                              void* d_out, int out_size, void* d_ws, size_t ws_size,
                              hipStream_t stream)
{
    const float* keys     = (const float*)d_in[0];
    const float* vals     = (const float*)d_in[1];
    const int*   lens_raw = (const int*)d_in[2];
    const float* W1       = (const float*)d_in[3];
    const float* W2       = (const float*)d_in[4];
    const float* W3       = (const float*)d_in[5];

    char* ws = (char*)d_ws;
    const size_t MB = 1024 * 1024;
    unsigned short* Akv  = (unsigned short*)ws;
    float*          P3   = (float*)ws;                       // over Akv (dead)
    unsigned short* P1b  = (unsigned short*)(ws + 64 * MB);
    unsigned short* Vt   = (unsigned short*)(ws + 64 * MB);  // over P1b (dead)
    unsigned short* Sb   = (unsigned short*)(ws + 128 * MB);
    unsigned short* W1b  = (unsigned short*)(ws + 192 * MB);
    unsigned short* W2b  = W1b + Hc * Hc;
    unsigned short* W3b  = W2b + Hc * Hc;
    unsigned short* attnT= (unsigned short*)(ws + 194 * MB);
    int*            lens = (int*)(ws + 202 * MB);

    float* out_attn   = (float*)d_out;
    float* out_class  = out_attn + (size_t)Bc * Lc * Cc;
    float* out_smooth = out_class + (size_t)Bc * Cc * Hc;

    hipMemsetAsync(out_class, 0, (size_t)Bc * Cc * Hc * sizeof(float), stream);

    f32_to_bf16_kernel<<<(Mc * Hc / 8) / 256, 256, 0, stream>>>(keys, Akv);
    convert_weights_kernel<<<272, 256, 0, stream>>>(W1, W2, W3, W1b, W2b, W3b);
    normalize_lens_kernel<<<1, 64, 0, stream>>>(lens_raw, lens);

    // P1 = tanh(keys @ W1^T)   [bf16 out]  (2048 linear blocks, XCD-grouped)
    mfma_gemm512<<<2048, 256, 0, stream>>>(Akv, W1b, P1b, 0);
    // S = P1 + tanh(P1 @ W2^T) [bf16 out]
    mfma_gemm512<<<2048, 256, 0, stream>>>(P1b, W2b, Sb, 1);
    // Vt = transpose(bf16(vals))  (P1b dead now; Vt overlays it)
    transpose_v_kernel<<<dim3(Lc / 64, Hc / 64, Bc), 256, 0, stream>>>(vals, Vt);
    // P3 = S @ W3^T            [fp32 out, stride 52, overlays dead Akv]
    mfma_gemm_p3<<<Mc / 128, 256, 0, stream>>>(Sb, W3b, P3);
    // pool + softmax + mask; also emits attnT bf16
    pool_softmax_kernel<<<Mc / 256, 256, 0, stream>>>(P3, lens, out_attn, out_smooth, attnT);
    // class_inputs = attnT @ Vt^T per batch (MFMA, K-split 4, atomic reduce)
    class_mfma_kernel<<<dim3(4, Bc, 4), 256, 0, stream>>>(attnT, Vt, out_class);
}